// Round 1
// baseline (576.873 us; speedup 1.0000x reference)
//
#include <hip/hip_runtime.h>

#define NEG_SLOPE 0.2f
#define NEG_INF   -1e9f

// ---------------------------------------------------------------------------
// Kernel 1: node embedding  h[1+n,:] = tf[n,:] @ W_emb + b_emb ; h[0,:] = 0
// ---------------------------------------------------------------------------
__global__ void embed_kernel(const float* __restrict__ tf,
                             const float* __restrict__ W_emb,
                             const float* __restrict__ b_emb,
                             float* __restrict__ h, int N) {
    int n = blockIdx.x * blockDim.x + threadIdx.x;
    if (n >= N) return;
    if (n == 0) {
        #pragma unroll
        for (int j = 0; j < 8; ++j) h[j] = 0.f;
    }
    const float4* tfr = reinterpret_cast<const float4*>(tf + (size_t)n * 8);
    float4 a = tfr[0], b = tfr[1];
    float x[8] = {a.x, a.y, a.z, a.w, b.x, b.y, b.z, b.w};
    float out[8];
    #pragma unroll
    for (int j = 0; j < 8; ++j) out[j] = b_emb[j];
    #pragma unroll
    for (int i = 0; i < 8; ++i)
        #pragma unroll
        for (int j = 0; j < 8; ++j)
            out[j] += x[i] * W_emb[i * 8 + j];
    float4* hr = reinterpret_cast<float4*>(h + (size_t)(n + 1) * 8);
    hr[0] = make_float4(out[0], out[1], out[2], out[3]);
    hr[1] = make_float4(out[4], out[5], out[6], out[7]);
}

// ---------------------------------------------------------------------------
// Kernel 2: one GAT iteration. 32 lanes per node, K=30 neighbor slots.
// ITER==1: msg gathered rows computed on-the-fly from fdg/rij @ W_dist.
// ITER==2: msg row = h_cur[edge_src[b_scope-1]] (dependent double gather).
// ---------------------------------------------------------------------------
template <int ITER>
__global__ void gat_iter_kernel(const float* __restrict__ h_cur,
                                float* __restrict__ h_next,
                                const int* __restrict__ b_scope,
                                const int* __restrict__ start_end_env,
                                const float* __restrict__ fdg,
                                const float* __restrict__ rij,
                                const int* __restrict__ edge_src,
                                const float* __restrict__ W_dist,
                                const float* __restrict__ b_dist,
                                const float* __restrict__ W_gat,
                                const float* __restrict__ a_src,
                                const float* __restrict__ a_dst,
                                int N, int K) {
    __shared__ float sWg[64];   // W_gat
    __shared__ float sWd[72];   // W_dist (iter 1 only)
    __shared__ float sbd[8];    // b_dist
    __shared__ float s_as[8];   // W_gat @ a_src
    __shared__ float s_ad[8];   // W_gat @ a_dst

    int tid = threadIdx.x;
    if (tid < 64) sWg[tid] = W_gat[tid];
    if (ITER == 1) {
        if (tid >= 64 && tid < 136) sWd[tid - 64] = W_dist[tid - 64];
        if (tid >= 136 && tid < 144) sbd[tid - 136] = b_dist[tid - 136];
    }
    __syncthreads();
    if (tid < 8) {
        float s = 0.f;
        #pragma unroll
        for (int j = 0; j < 8; ++j) s += sWg[tid * 8 + j] * a_src[j];
        s_as[tid] = s;
    } else if (tid < 16) {
        int i = tid - 8;
        float s = 0.f;
        #pragma unroll
        for (int j = 0; j < 8; ++j) s += sWg[i * 8 + j] * a_dst[j];
        s_ad[i] = s;
    }
    __syncthreads();

    if (blockIdx.x == 0 && tid < 8) h_next[tid] = 0.f;  // zero row

    int gid  = blockIdx.x * blockDim.x + tid;
    int node = gid >> 5;
    int k    = tid & 31;
    if (node >= N) return;
    bool valid = (k < K);

    float msg[8];
    #pragma unroll
    for (int j = 0; j < 8; ++j) msg[j] = 0.f;
    float e = -3e38f;  // lanes k>=K never win the max

    if (valid) {
        int bs = b_scope[(size_t)node * K + k];
        int se = start_end_env[(size_t)node * K + k];
        const float4* hr = reinterpret_cast<const float4*>(h_cur + (size_t)se * 8);
        float4 h0 = hr[0], h1 = hr[1];
        float s_s = h0.x * s_as[0] + h0.y * s_as[1] + h0.z * s_as[2] + h0.w * s_as[3]
                  + h1.x * s_as[4] + h1.y * s_as[5] + h1.z * s_as[6] + h1.w * s_as[7];
        if (bs > 0) {
            if (ITER == 1) {
                int ei = bs - 1;
                const float4* fr = reinterpret_cast<const float4*>(fdg + (size_t)ei * 8);
                float4 f0 = fr[0], f1 = fr[1];
                float xx[9] = {f0.x, f0.y, f0.z, f0.w, f1.x, f1.y, f1.z, f1.w, rij[ei]};
                #pragma unroll
                for (int j = 0; j < 8; ++j) {
                    float s = sbd[j];
                    #pragma unroll
                    for (int i = 0; i < 9; ++i) s += xx[i] * sWd[i * 8 + j];
                    msg[j] = s;
                }
            } else {
                int src = edge_src[bs - 1];
                const float4* mr = reinterpret_cast<const float4*>(h_cur + (size_t)src * 8);
                float4 m0 = mr[0], m1 = mr[1];
                msg[0] = m0.x; msg[1] = m0.y; msg[2] = m0.z; msg[3] = m0.w;
                msg[4] = m1.x; msg[5] = m1.y; msg[6] = m1.z; msg[7] = m1.w;
            }
        }
        float s_m = 0.f;
        #pragma unroll
        for (int j = 0; j < 8; ++j) s_m += msg[j] * s_ad[j];
        float ee = s_s + s_m;
        ee = (ee >= 0.f) ? ee : NEG_SLOPE * ee;   // leaky relu
        e  = (bs > 0) ? ee : NEG_INF;             // pad mask
    }

    // softmax over the 32-lane group (lanes k>=K contribute 0)
    float m = e;
    #pragma unroll
    for (int off = 16; off; off >>= 1) m = fmaxf(m, __shfl_xor(m, off, 32));
    float p = valid ? expf(e - m) : 0.f;
    float denom = p;
    #pragma unroll
    for (int off = 16; off; off >>= 1) denom += __shfl_xor(denom, off, 32);
    float alpha = p / denom;

    // weighted aggregate of msg rows (8-wide butterfly)
    float agg[8];
    #pragma unroll
    for (int j = 0; j < 8; ++j) agg[j] = alpha * msg[j];
    #pragma unroll
    for (int off = 16; off; off >>= 1)
        #pragma unroll
        for (int j = 0; j < 8; ++j) agg[j] += __shfl_xor(agg[j], off, 32);

    // lanes 0..7: out_j = (agg @ W_gat)_j, then ELU, store
    if (k < 8) {
        float o = 0.f;
        #pragma unroll
        for (int i = 0; i < 8; ++i) o += agg[i] * sWg[i * 8 + k];
        o = (o > 0.f) ? o : (expf(o) - 1.f);      // elu
        h_next[(size_t)(node + 1) * 8 + k] = o;
    }
}

// ---------------------------------------------------------------------------
// Kernel 3: readout  out[b,:] = sum_l h[l_scope[b,l], :]
// ---------------------------------------------------------------------------
__global__ void readout_kernel(const float* __restrict__ h,
                               const int* __restrict__ l_scope,
                               float* __restrict__ out, int B, int L) {
    int gid = blockIdx.x * blockDim.x + threadIdx.x;
    int b = gid >> 3;
    int j = gid & 7;
    if (b >= B) return;
    float s = 0.f;
    for (int l = 0; l < L; ++l) {
        int idx = l_scope[(size_t)b * L + l];
        s += h[(size_t)idx * 8 + j];
    }
    out[(size_t)b * 8 + j] = s;
}

// ---------------------------------------------------------------------------
extern "C" void kernel_launch(void* const* d_in, const int* in_sizes, int n_in,
                              void* d_out, int out_size, void* d_ws, size_t ws_size,
                              hipStream_t stream) {
    const float* tf      = (const float*)d_in[0];
    const float* fdg     = (const float*)d_in[1];
    const float* rij     = (const float*)d_in[2];
    const int* b_scope   = (const int*)d_in[3];
    const int* start_env = (const int*)d_in[4];
    const int* l_scope   = (const int*)d_in[5];
    const int* edge_src  = (const int*)d_in[6];
    const float* W_emb   = (const float*)d_in[7];
    const float* b_emb   = (const float*)d_in[8];
    const float* W_dist  = (const float*)d_in[9];
    const float* b_dist  = (const float*)d_in[10];
    const float* W_gat   = (const float*)d_in[11];
    const float* a_src   = (const float*)d_in[12];
    const float* a_dst   = (const float*)d_in[13];
    float* out = (float*)d_out;

    const int N = in_sizes[0] / 8;          // 204800
    const int K = in_sizes[3] / N;          // 30
    const int L = 50;
    const int B = in_sizes[5] / L;          // 4096

    float* h_a = (float*)d_ws;              // (N+1)*8 floats
    float* h_b = h_a + (size_t)(N + 1) * 8; // (N+1)*8 floats

    embed_kernel<<<(N + 255) / 256, 256, 0, stream>>>(tf, W_emb, b_emb, h_a, N);

    dim3 gblk(((size_t)N * 32 + 255) / 256);
    gat_iter_kernel<1><<<gblk, 256, 0, stream>>>(h_a, h_b, b_scope, start_env,
                                                 fdg, rij, edge_src,
                                                 W_dist, b_dist, W_gat, a_src, a_dst, N, K);
    gat_iter_kernel<2><<<gblk, 256, 0, stream>>>(h_b, h_a, b_scope, start_env,
                                                 fdg, rij, edge_src,
                                                 W_dist, b_dist, W_gat, a_src, a_dst, N, K);

    readout_kernel<<<(B * 8 + 255) / 256, 256, 0, stream>>>(h_a, l_scope, out, B, L);
}